// Round 6
// baseline (190.035 us; speedup 1.0000x reference)
//
#include <hip/hip_runtime.h>
#include <stdint.h>

// ---------------------------------------------------------------------------
// MHA forward: fp32 in/out, internal bf16, fp32 accumulate.
//   B=4 S=2048 D=512 H=8 DH=64
//   pipeline: convert(fp32->bf16) -> merged QKV NT-GEMM (DMA-staged) ->
//             flash attention (64-key dbuf tiles, QBLK=128) -> out-proj GEMM
// MFMA 16x16x32 bf16 layouts (HW-verified per guide):
//   A-frag: lane holds A[m=lane&15][k=(lane>>4)*8 + j], j=0..7 (contiguous)
//   B-frag: lane holds B[k=(lane>>4)*8 + j][n=lane&15]
//   C/D   : lane reg r holds D[row=(lane>>4)*4 + r][col=lane&15]
// NOTE (rounds 4-5): swapped-operand QK^T (mfma(K,Q)) failed with ~1.85
//   absmax, non-deterministic across builds, unexplained by layout algebra
//   or compiler-ordering fixes. ABANDONED — attn uses the R2-verified
//   orientation; this round changes GEOMETRY only (QBLK 64->128).
// ---------------------------------------------------------------------------

typedef __attribute__((ext_vector_type(8))) short short8;
typedef __attribute__((ext_vector_type(4))) float f32x4;
typedef __attribute__((ext_vector_type(4))) unsigned short u16x4;

#define MFMA16(a, b, c) __builtin_amdgcn_mfma_f32_16x16x32_bf16(a, b, c, 0, 0, 0)

#define SCALE_LOG2 0.18033688011112042f
#define FIXED_M    32.0f
#define MASKED_E2  -200.0f   // exp2(-200) == 0.0f exactly

__device__ __forceinline__ unsigned short f2bf(float f) {
    unsigned int x = __float_as_uint(f);
    unsigned int r = (x + 0x7fffu + ((x >> 16) & 1u)) >> 16;  // RNE
    return (unsigned short)r;
}
__device__ __forceinline__ short8 load8(const unsigned short* p) {
    return *reinterpret_cast<const short8*>(p);
}
// async 16B global -> LDS DMA (lane l lands at lds + l*16)
__device__ __forceinline__ void gload_lds16(const unsigned short* g, unsigned short* l) {
    __builtin_amdgcn_global_load_lds(
        (const __attribute__((address_space(1))) unsigned int*)g,
        (__attribute__((address_space(3))) unsigned int*)l, 16, 0, 0);
}

// ---------------------------------------------------------------------------
// fp32 -> bf16 convert: Q,K,V (3 x 4.19M) + Wq,Wk,Wv,Wo (4 x 262144) into ws,
// contiguous in source order (so dst index == flat float4 index).
// ---------------------------------------------------------------------------
__global__ __launch_bounds__(256)
void convert_bf16(const float4* __restrict__ Q, const float4* __restrict__ K,
                  const float4* __restrict__ V, const float4* __restrict__ Wq,
                  const float4* __restrict__ Wk, const float4* __restrict__ Wv,
                  const float4* __restrict__ Wo, u16x4* __restrict__ dst)
{
    const int n = 3407872;  // 3*1048576 + 4*65536 float4s
    for (int i = blockIdx.x * 256 + threadIdx.x; i < n; i += gridDim.x * 256) {
        const float4* src; int off;
        if      (i < 1048576) { src = Q;  off = i; }
        else if (i < 2097152) { src = K;  off = i - 1048576; }
        else if (i < 3145728) { src = V;  off = i - 2097152; }
        else if (i < 3211264) { src = Wq; off = i - 3145728; }
        else if (i < 3276800) { src = Wk; off = i - 3211264; }
        else if (i < 3342336) { src = Wv; off = i - 3276800; }
        else                  { src = Wo; off = i - 3342336; }
        const float4 v = src[off];
        u16x4 r;
        r[0] = f2bf(v.x); r[1] = f2bf(v.y); r[2] = f2bf(v.z); r[3] = f2bf(v.w);
        dst[i] = r;
    }
}

// ---------------------------------------------------------------------------
// NT GEMM, bf16 x bf16, 128x128 tile, BK=64, 256 thr = 4 waves (2x2 of 64x64).
// C[i][j] = sum_k A[i][k]*W[j][k] + bias[j];  A [8192,512], W [512,512].
// DMA staging (global_load_lds 16B), pre-swizzled source, 32 KB LDS ->
// 5 blocks/CU (round-3 post-mortem: occupancy beats dbuf fusion here).
// ---------------------------------------------------------------------------
__global__ __launch_bounds__(256)
void gemm_bf(const unsigned short* __restrict__ Aall,
             const unsigned short* __restrict__ Wall,
             const float* __restrict__ b0, const float* __restrict__ b1,
             const float* __restrict__ b2,
             void* __restrict__ outall, int out_mode)
{
    __shared__ unsigned short As[128 * 64];
    __shared__ unsigned short Bs[128 * 64];

    const int z = blockIdx.y;
    const unsigned short* A = Aall + (long)z * 4194304;
    const unsigned short* W = Wall + z * 262144;
    const float* bias = (z == 0) ? b0 : (z == 1) ? b1 : b2;
    void* out = (out_mode == 0)
        ? (void*)((unsigned short*)outall + (long)z * 4194304) : outall;

    const int f    = blockIdx.x;       // 0..255
    const int xcd  = f & 7;
    const int slot = f >> 3;
    const int col0 = (slot & 3) * 128;
    const int row0 = ((slot >> 2) * 8 + xcd) * 128;

    const int tid  = threadIdx.x;
    const int lane = tid & 63;
    const int w    = tid >> 6;
    const int quad = lane >> 4;
    const int nlow = lane & 15;
    const int wm   = w >> 1, wn = w & 1;

    const unsigned short* ag[4];
    const unsigned short* wg[4];
    unsigned short *la[4], *lb[4];
#pragma unroll
    for (int i = 0; i < 4; i++) {
        const int s = i * 256 + tid;
        const int r = s >> 3, kcl = s & 7;
        const int kg = kcl ^ (r & 7);
        ag[i] = A + (long)(row0 + r) * 512 + kg * 8;
        wg[i] = W + (long)(col0 + r) * 512 + kg * 8;
        const int ldso = i * 2048 + ((tid >> 6) << 9);  // wave-uniform base
        la[i] = As + ldso;
        lb[i] = Bs + ldso;
    }

    f32x4 acc[4][4];
#pragma unroll
    for (int t = 0; t < 4; t++)
#pragma unroll
        for (int g = 0; g < 4; g++) acc[t][g] = (f32x4){0.f, 0.f, 0.f, 0.f};

    for (int k0 = 0; k0 < 512; k0 += 64) {
#pragma unroll
        for (int i = 0; i < 4; i++) {
            gload_lds16(ag[i] + k0, la[i]);
            gload_lds16(wg[i] + k0, lb[i]);
        }
        __syncthreads();

        short8 af[4][2], bf[4][2];
#pragma unroll
        for (int t = 0; t < 4; t++) {
            const int rowa = wm * 64 + t * 16 + nlow;
            const int rowb = wn * 64 + t * 16 + nlow;
#pragma unroll
            for (int kc = 0; kc < 2; kc++) {
                const int c = (kc * 4 + quad) ^ (nlow & 7);
                af[t][kc] = load8(&As[(rowa * 8 + c) * 8]);
                bf[t][kc] = load8(&Bs[(rowb * 8 + c) * 8]);
            }
        }
#pragma unroll
        for (int kc = 0; kc < 2; kc++)
#pragma unroll
            for (int t = 0; t < 4; t++)
#pragma unroll
                for (int g = 0; g < 4; g++)
                    acc[t][g] = MFMA16(af[t][kc], bf[g][kc], acc[t][g]);
        __syncthreads();
    }

#pragma unroll
    for (int g = 0; g < 4; g++) {
        const int j = col0 + wn * 64 + g * 16 + nlow;
        const float bj = bias[j];
#pragma unroll
        for (int t = 0; t < 4; t++) {
#pragma unroll
            for (int r = 0; r < 4; r++) {
                const int i = row0 + wm * 64 + t * 16 + quad * 4 + r;
                const float v = acc[t][g][r] + bj;
                if (out_mode == 0) {
                    const int b = i >> 11, s = i & 2047;
                    const int h = j >> 6, dh = j & 63;
                    ((unsigned short*)out)[(((b * 8 + h) * 2048) + s) * 64 + dh] = f2bf(v);
                } else {
                    ((float*)out)[(long)i * 512 + j] = v;
                }
            }
        }
    }
}

// ---------------------------------------------------------------------------
// Flash attention, fixed-offset softmax. R2-verified layouts/orientation;
// round-6 geometry change: QBLK 64 -> 128 (each wave owns 32 q-rows in two
// 16-row groups). Shared bk/bv LDS reads + K/V staging amortized over 2x
// q-work: per-128-q b128 reads 36->20, b16 writes 64->48, MFMA unchanged.
//   * 64-key tiles, double-buffered K/V, ONE __syncthreads per tile.
//   * async-STAGE split; K via global_load_lds pre-swizzled source;
//     Vt/Ps XOR-swizzled unpadded LDS; 48 KB LDS, grid 512 -> 2 blocks/CU.
//   * T5 setprio(1) around QK^T and PV MFMA clusters.
//   * XCD-aware grid: h = f&7 -> one head per XCD, all batches per XCD.
// qp/kp/vp: [B,H,S,64] bf16. out: [B,S,512] bf16.
// ---------------------------------------------------------------------------
__device__ __forceinline__ int ks_idx(int key, int dchunk) {
    return key * 64 + ((dchunk ^ (key & 7)) << 3);
}
__device__ __forceinline__ int vt_idx(int key, int dh) {
    return dh * 64 + ((((key >> 3) ^ (dh & 7) ^ ((dh >> 3) & 7)) << 3) + (key & 7));
}
__device__ __forceinline__ int ps_idx(int q, int key) {
    return q * 64 + ((((key >> 3) ^ (q & 7)) << 3) + (key & 7));
}

__global__ __launch_bounds__(256, 2)
void attn_kernel(const unsigned short* __restrict__ qp,
                 const unsigned short* __restrict__ kp,
                 const unsigned short* __restrict__ vp,
                 const void* __restrict__ masked,
                 unsigned short* __restrict__ out)
{
    __shared__ unsigned short Ks[2][4096];   // [buf][key*64 + swz_chunk*8+e]
    __shared__ unsigned short Vt[2][4096];   // [buf][dh*64 + swz_col]
    __shared__ unsigned short Ps[4][2048];   // [wave][qg*1024 + q*64 + swz]

    const int tid  = threadIdx.x;
    const int lane = tid & 63;
    const int w    = tid >> 6;
    const int quad = lane >> 4;
    const int nlow = lane & 15;

    // XCD-aware block decode (blocks round-robin XCDs by id%8)
    const int f  = blockIdx.x;          // 0..511
    const int h  = f & 7;
    const int qb = (f >> 3) & 15;
    const int b  = f >> 7;
    const int q0 = qb * 128 + w * 32;
    const long base = ((long)(b * 8 + h)) * 2048 * 64;

    const long long first = *reinterpret_cast<const long long*>(masked);
    int kmax;
    if ((first >> 32) != 0) kmax = reinterpret_cast<const int*>(masked)[b];
    else                    kmax = (int)reinterpret_cast<const long long*>(masked)[b];
    kmax = min(max(kmax, 1), 2048);
    const int nkt = (kmax + 63) >> 6;

    // Q fragments: two 16-row groups per wave
    short8 aq[2][2];
#pragma unroll
    for (int qg = 0; qg < 2; qg++) {
        const unsigned short* qrow = qp + base + (long)(q0 + qg * 16 + nlow) * 64;
        aq[qg][0] = load8(qrow + quad * 8);
        aq[qg][1] = load8(qrow + 32 + quad * 8);
    }

    short8 ones;
#pragma unroll
    for (int j = 0; j < 8; j++) ones[j] = (short)0x3F80;

    f32x4 o_acc[2][4], lacc[2];
#pragma unroll
    for (int qg = 0; qg < 2; qg++) {
#pragma unroll
        for (int vb = 0; vb < 4; vb++) o_acc[qg][vb] = (f32x4){0.f, 0.f, 0.f, 0.f};
        lacc[qg] = (f32x4){0.f, 0.f, 0.f, 0.f};
    }

    // --- staging descriptors (verbatim R2) -----------------------------------
    const int kr0 = tid >> 3;
    const int kr1 = 32 + kr0;
    const unsigned short* kg0 = kp + base + (long)kr0 * 64 + (((tid & 7) ^ (kr0 & 7)) << 3);
    const unsigned short* kg1 = kp + base + (long)kr1 * 64 + (((tid & 7) ^ (kr1 & 7)) << 3);
    const int kd0 = (w << 9);           // wave-uniform LDS elem offset, round 0
    const int kd1 = 2048 + (w << 9);    // round 1
    const int vk0 = tid >> 3;
    const int vk1 = 32 + vk0;
    const int vd0 = (tid & 7) << 3;
    const unsigned short* vg0 = vp + base + (long)vk0 * 64 + vd0;
    const unsigned short* vg1 = vp + base + (long)vk1 * 64 + vd0;

    // --- prologue: stage tile 0 into buffer 0 --------------------------------
    gload_lds16(kg0, &Ks[0][kd0]);
    gload_lds16(kg1, &Ks[0][kd1]);
    {
        short8 v0 = load8(vg0);
        short8 v1 = load8(vg1);
#pragma unroll
        for (int j = 0; j < 8; j++) {
            Vt[0][vt_idx(vk0, vd0 + j)] = (unsigned short)v0[j];
            Vt[0][vt_idx(vk1, vd0 + j)] = (unsigned short)v1[j];
        }
    }
    __syncthreads();   // drains DMA vmcnt + V ds_writes

    unsigned short* Psw = Ps[w];
    int cur = 0;
    short8 vv0, vv1;

    for (int kt = 0; kt < nkt; kt++) {
        const int k0 = kt * 64;
        const bool more = (kt + 1 < nkt);   // block-uniform
        if (more) {
            const long off = (long)(k0 + 64) * 64;
            gload_lds16(kg0 + off, &Ks[cur ^ 1][kd0]);
            gload_lds16(kg1 + off, &Ks[cur ^ 1][kd1]);
            vv0 = load8(vg0 + off);
            vv1 = load8(vg1 + off);
        }
        const unsigned short* Ksc = Ks[cur];
        const unsigned short* Vtc = Vt[cur];

        // ---- QK^T, both q-groups share the bk reads ------------------------
        f32x4 sacc[2][4];
#pragma unroll
        for (int qg = 0; qg < 2; qg++)
#pragma unroll
            for (int kb = 0; kb < 4; kb++) sacc[qg][kb] = (f32x4){0.f, 0.f, 0.f, 0.f};
        __builtin_amdgcn_s_setprio(1);
#pragma unroll
        for (int kb = 0; kb < 4; kb++) {
            const int key = kb * 16 + nlow;
            short8 bk0 = load8(Ksc + ks_idx(key, quad));
            short8 bk1 = load8(Ksc + ks_idx(key, 4 + quad));
#pragma unroll
            for (int qg = 0; qg < 2; qg++) {
                sacc[qg][kb] = MFMA16(aq[qg][0], bk0, sacc[qg][kb]);
                sacc[qg][kb] = MFMA16(aq[qg][1], bk1, sacc[qg][kb]);
            }
        }
        __builtin_amdgcn_s_setprio(0);

        // ---- fixed-offset softmax -> Ps (bf16), verbatim R2 per group ------
#pragma unroll
        for (int qg = 0; qg < 2; qg++) {
            const int pb = qg << 10;
#pragma unroll
            for (int kb = 0; kb < 4; kb++) {
                const bool valid = (k0 + kb * 16 + nlow) < kmax;
#pragma unroll
                for (int r = 0; r < 4; r++) {
                    const int q = quad * 4 + r;
                    const float e = valid ? fmaf(sacc[qg][kb][r], SCALE_LOG2, -FIXED_M)
                                          : MASKED_E2;
                    Psw[pb + ps_idx(q, kb * 16 + nlow)] = f2bf(exp2f(e));
                }
            }
        }
        __threadfence_block();   // same-wave Ps RAW ordering

        // ---- l-sum + PV: bv reads shared across q-groups --------------------
        __builtin_amdgcn_s_setprio(1);
#pragma unroll
        for (int h2 = 0; h2 < 2; h2++) {
            const int g = h2 * 4 + quad;            // key-chunk group
            short8 bv[4];
#pragma unroll
            for (int vb = 0; vb < 4; vb++)
                bv[vb] = load8(Vtc + vt_idx(g << 3, vb * 16 + nlow));
#pragma unroll
            for (int qg = 0; qg < 2; qg++) {
                short8 ap = load8(&Psw[(qg << 10) + ps_idx(nlow, g << 3)]);
                lacc[qg] = MFMA16(ap, ones, lacc[qg]);
#pragma unroll
                for (int vb = 0; vb < 4; vb++)
                    o_acc[qg][vb] = MFMA16(ap, bv[vb], o_acc[qg][vb]);
            }
        }
        __builtin_amdgcn_s_setprio(0);

        // ---- late half of the async stage: V regs -> LDS --------------------
        if (more) {
            unsigned short* Vtn = Vt[cur ^ 1];
#pragma unroll
            for (int j = 0; j < 8; j++) {
                Vtn[vt_idx(vk0, vd0 + j)] = (unsigned short)vv0[j];
                Vtn[vt_idx(vk1, vd0 + j)] = (unsigned short)vv1[j];
            }
        }
        __syncthreads();   // one barrier per 64-key tile
        cur ^= 1;
    }

#pragma unroll
    for (int qg = 0; qg < 2; qg++) {
        float inv_l[4];
#pragma unroll
        for (int r = 0; r < 4; r++) inv_l[r] = 1.0f / lacc[qg][r];
#pragma unroll
        for (int vb = 0; vb < 4; vb++) {
#pragma unroll
            for (int r = 0; r < 4; r++) {
                const int s   = q0 + qg * 16 + quad * 4 + r;
                const int col = h * 64 + vb * 16 + nlow;
                out[(long)(b * 2048 + s) * 512 + col] = f2bf(o_acc[qg][vb][r] * inv_l[r]);
            }
        }
    }
}

// ---------------------------------------------------------------------------
// ws layout (u16 elems):
//   [0)          QKVb   3 x 4194304   (bf16 copies of Q,K,V; Qb aliased by ao)
//   [12582912)   Wb     4 x 262144    (Wq,Wk,Wv,Wo bf16)
//   [13631488)   qp,kp,vp  3 x 4194304
// total 26.2M u16 = 52.4 MB
// ---------------------------------------------------------------------------
extern "C" void kernel_launch(void* const* d_in, const int* in_sizes, int n_in,
                              void* d_out, int out_size, void* d_ws, size_t ws_size,
                              hipStream_t stream)
{
    const float4* Q  = (const float4*)d_in[0];
    const float4* K  = (const float4*)d_in[1];
    const float4* V  = (const float4*)d_in[2];
    const float4* Wq = (const float4*)d_in[3];
    const float*  bq = (const float*)d_in[4];
    const float4* Wk = (const float4*)d_in[5];
    const float*  bk = (const float*)d_in[6];
    const float4* Wv = (const float4*)d_in[7];
    const float*  bv = (const float*)d_in[8];
    const float4* Wo = (const float4*)d_in[9];
    const float*  bo = (const float*)d_in[10];
    const void*   masked = d_in[11];

    unsigned short* ws16 = (unsigned short*)d_ws;
    unsigned short* QKVb = ws16;
    unsigned short* Wb   = ws16 + 12582912;
    unsigned short* qp   = ws16 + 13631488;
    unsigned short* kp   = qp + 4194304;
    unsigned short* vp   = kp + 4194304;
    unsigned short* ao   = ws16;  // alias Qb: Qb consumed before attn writes ao

    convert_bf16<<<2048, 256, 0, stream>>>(Q, K, V, Wq, Wk, Wv, Wo, (u16x4*)ws16);
    gemm_bf<<<dim3(256, 3), 256, 0, stream>>>(QKVb, Wb, bq, bk, bv, qp, 0);
    attn_kernel<<<dim3(512), 256, 0, stream>>>(qp, kp, vp, masked, ao);
    gemm_bf<<<dim3(256, 1), 256, 0, stream>>>(ao, Wb + 3 * 262144, bo, bo, bo,
                                              d_out, 1);
}

// Round 7
// 175.837 us; speedup vs baseline: 1.0807x; 1.0807x over previous
//
#include <hip/hip_runtime.h>
#include <stdint.h>

// ---------------------------------------------------------------------------
// MHA forward: fp32 in/out, internal bf16, fp32 accumulate.
//   B=4 S=2048 D=512 H=8 DH=64
//   pipeline: convert(fp32->bf16) -> merged QKV NT-GEMM (DMA-staged) ->
//             flash attention (64-key dbuf tiles, 1 barrier/tile) ->
//             out-proj NT-GEMM
// MFMA 16x16x32 bf16 layouts (HW-verified per guide):
//   A-frag: lane holds A[m=lane&15][k=(lane>>4)*8 + j], j=0..7 (contiguous)
//   B-frag: lane holds B[k=(lane>>4)*8 + j][n=lane&15]
//   C/D   : lane reg r holds D[row=(lane>>4)*4 + r][col=lane&15]
// History:
//   R2  = this structure, 176.2 us (best verified).
//   R3  (fused convert+GEMM, reg-staged dbuf)  -> 182.6: occupancy loss.
//   R4/5 (swapped QK^T)                        -> FAILED ~1.85 absmax. Abandoned.
//   R6  (QBLK=128, 2 blocks/CU)                -> 190.0: attn latency-bound,
//        lost TLP. Revert to R2 geometry.
//   R7  = R2 + T5 s_setprio around attn MFMA clusters (isolated, zero-risk).
// ---------------------------------------------------------------------------

typedef __attribute__((ext_vector_type(8))) short short8;
typedef __attribute__((ext_vector_type(4))) short short4v;
typedef __attribute__((ext_vector_type(4))) float f32x4;
typedef __attribute__((ext_vector_type(4))) unsigned short u16x4;

#define MFMA16(a, b, c) __builtin_amdgcn_mfma_f32_16x16x32_bf16(a, b, c, 0, 0, 0)

#define SCALE_LOG2 0.18033688011112042f
#define FIXED_M    32.0f
#define MASKED_E2  -200.0f   // exp2(-200) == 0.0f exactly

__device__ __forceinline__ unsigned short f2bf(float f) {
    unsigned int x = __float_as_uint(f);
    unsigned int r = (x + 0x7fffu + ((x >> 16) & 1u)) >> 16;  // RNE
    return (unsigned short)r;
}
__device__ __forceinline__ short8 load8(const unsigned short* p) {
    return *reinterpret_cast<const short8*>(p);
}
// async 16B global -> LDS DMA (lane l lands at lds + l*16)
__device__ __forceinline__ void gload_lds16(const unsigned short* g, unsigned short* l) {
    __builtin_amdgcn_global_load_lds(
        (const __attribute__((address_space(1))) unsigned int*)g,
        (__attribute__((address_space(3))) unsigned int*)l, 16, 0, 0);
}

// ---------------------------------------------------------------------------
// fp32 -> bf16 convert: Q,K,V (3 x 4.19M) + Wq,Wk,Wv,Wo (4 x 262144) into ws,
// contiguous in source order (so dst index == flat float4 index).
// ---------------------------------------------------------------------------
__global__ __launch_bounds__(256)
void convert_bf16(const float4* __restrict__ Q, const float4* __restrict__ K,
                  const float4* __restrict__ V, const float4* __restrict__ Wq,
                  const float4* __restrict__ Wk, const float4* __restrict__ Wv,
                  const float4* __restrict__ Wo, u16x4* __restrict__ dst)
{
    const int n = 3407872;  // 3*1048576 + 4*65536 float4s
    for (int i = blockIdx.x * 256 + threadIdx.x; i < n; i += gridDim.x * 256) {
        const float4* src; int off;
        if      (i < 1048576) { src = Q;  off = i; }
        else if (i < 2097152) { src = K;  off = i - 1048576; }
        else if (i < 3145728) { src = V;  off = i - 2097152; }
        else if (i < 3211264) { src = Wq; off = i - 3145728; }
        else if (i < 3276800) { src = Wk; off = i - 3211264; }
        else if (i < 3342336) { src = Wv; off = i - 3276800; }
        else                  { src = Wo; off = i - 3342336; }
        const float4 v = src[off];
        u16x4 r;
        r[0] = f2bf(v.x); r[1] = f2bf(v.y); r[2] = f2bf(v.z); r[3] = f2bf(v.w);
        dst[i] = r;
    }
}

// ---------------------------------------------------------------------------
// NT GEMM, bf16 x bf16, 128x128 tile, BK=64, 256 thr = 4 waves (2x2 of 64x64).
// C[i][j] = sum_k A[i][k]*W[j][k] + bias[j];  A [8192,512], W [512,512].
// DMA staging (global_load_lds 16B), pre-swizzled source, 32 KB LDS ->
// high occupancy (R3 post-mortem: occupancy beats dbuf fusion here).
// ---------------------------------------------------------------------------
__global__ __launch_bounds__(256)
void gemm_bf(const unsigned short* __restrict__ Aall,
             const unsigned short* __restrict__ Wall,
             const float* __restrict__ b0, const float* __restrict__ b1,
             const float* __restrict__ b2,
             void* __restrict__ outall, int out_mode)
{
    __shared__ unsigned short As[128 * 64];
    __shared__ unsigned short Bs[128 * 64];

    const int z = blockIdx.y;
    const unsigned short* A = Aall + (long)z * 4194304;
    const unsigned short* W = Wall + z * 262144;
    const float* bias = (z == 0) ? b0 : (z == 1) ? b1 : b2;
    void* out = (out_mode == 0)
        ? (void*)((unsigned short*)outall + (long)z * 4194304) : outall;

    const int f    = blockIdx.x;       // 0..255
    const int xcd  = f & 7;
    const int slot = f >> 3;
    const int col0 = (slot & 3) * 128;
    const int row0 = ((slot >> 2) * 8 + xcd) * 128;

    const int tid  = threadIdx.x;
    const int lane = tid & 63;
    const int w    = tid >> 6;
    const int quad = lane >> 4;
    const int nlow = lane & 15;
    const int wm   = w >> 1, wn = w & 1;

    const unsigned short* ag[4];
    const unsigned short* wg[4];
    unsigned short *la[4], *lb[4];
#pragma unroll
    for (int i = 0; i < 4; i++) {
        const int s = i * 256 + tid;
        const int r = s >> 3, kcl = s & 7;
        const int kg = kcl ^ (r & 7);
        ag[i] = A + (long)(row0 + r) * 512 + kg * 8;
        wg[i] = W + (long)(col0 + r) * 512 + kg * 8;
        const int ldso = i * 2048 + ((tid >> 6) << 9);  // wave-uniform base
        la[i] = As + ldso;
        lb[i] = Bs + ldso;
    }

    f32x4 acc[4][4];
#pragma unroll
    for (int t = 0; t < 4; t++)
#pragma unroll
        for (int g = 0; g < 4; g++) acc[t][g] = (f32x4){0.f, 0.f, 0.f, 0.f};

    for (int k0 = 0; k0 < 512; k0 += 64) {
#pragma unroll
        for (int i = 0; i < 4; i++) {
            gload_lds16(ag[i] + k0, la[i]);
            gload_lds16(wg[i] + k0, lb[i]);
        }
        __syncthreads();

        short8 af[4][2], bf[4][2];
#pragma unroll
        for (int t = 0; t < 4; t++) {
            const int rowa = wm * 64 + t * 16 + nlow;
            const int rowb = wn * 64 + t * 16 + nlow;
#pragma unroll
            for (int kc = 0; kc < 2; kc++) {
                const int c = (kc * 4 + quad) ^ (nlow & 7);
                af[t][kc] = load8(&As[(rowa * 8 + c) * 8]);
                bf[t][kc] = load8(&Bs[(rowb * 8 + c) * 8]);
            }
        }
#pragma unroll
        for (int kc = 0; kc < 2; kc++)
#pragma unroll
            for (int t = 0; t < 4; t++)
#pragma unroll
                for (int g = 0; g < 4; g++)
                    acc[t][g] = MFMA16(af[t][kc], bf[g][kc], acc[t][g]);
        __syncthreads();
    }

#pragma unroll
    for (int g = 0; g < 4; g++) {
        const int j = col0 + wn * 64 + g * 16 + nlow;
        const float bj = bias[j];
#pragma unroll
        for (int t = 0; t < 4; t++) {
#pragma unroll
            for (int r = 0; r < 4; r++) {
                const int i = row0 + wm * 64 + t * 16 + quad * 4 + r;
                const float v = acc[t][g][r] + bj;
                if (out_mode == 0) {
                    const int b = i >> 11, s = i & 2047;
                    const int h = j >> 6, dh = j & 63;
                    ((unsigned short*)out)[(((b * 8 + h) * 2048) + s) * 64 + dh] = f2bf(v);
                } else {
                    ((float*)out)[(long)i * 512 + j] = v;
                }
            }
        }
    }
}

// ---------------------------------------------------------------------------
// Flash attention, fixed-offset softmax. R2-verified (176.2 us) geometry:
//   * 64-key tiles, double-buffered K/V, ONE __syncthreads per tile.
//   * async-STAGE split; K via global_load_lds pre-swizzled source;
//     Vt/Ps XOR-swizzled unpadded LDS (40960 B -> 4 blocks/CU, 16 waves/CU).
//   * XCD-aware grid: h = f&7 -> one head per XCD, all batches per XCD.
//   * R7 delta: T5 s_setprio(1) around the QK^T and PV MFMA clusters only.
// qp/kp/vp: [B,H,S,64] bf16. out: [B,S,512] bf16.
// ---------------------------------------------------------------------------
__device__ __forceinline__ int ks_idx(int key, int dchunk) {
    return key * 64 + ((dchunk ^ (key & 7)) << 3);
}
__device__ __forceinline__ int vt_idx(int key, int dh) {
    return dh * 64 + ((((key >> 3) ^ (dh & 7) ^ ((dh >> 3) & 7)) << 3) + (key & 7));
}
__device__ __forceinline__ int ps_idx(int q, int key) {
    return q * 64 + ((((key >> 3) ^ (q & 7)) << 3) + (key & 7));
}

__global__ __launch_bounds__(256, 4)
void attn_kernel(const unsigned short* __restrict__ qp,
                 const unsigned short* __restrict__ kp,
                 const unsigned short* __restrict__ vp,
                 const void* __restrict__ masked,
                 unsigned short* __restrict__ out)
{
    __shared__ unsigned short Ks[2][4096];   // [buf][key*64 + swz_chunk*8+e]
    __shared__ unsigned short Vt[2][4096];   // [buf][dh*64 + swz_col]
    __shared__ unsigned short Ps[4][1024];   // [wave][q*64 + swz_chunk*8+e]

    const int tid  = threadIdx.x;
    const int lane = tid & 63;
    const int w    = tid >> 6;
    const int quad = lane >> 4;
    const int nlow = lane & 15;

    // XCD-aware block decode (blocks round-robin XCDs by id%8)
    const int f  = blockIdx.x;          // 0..1023
    const int h  = f & 7;
    const int qb = (f >> 3) & 31;
    const int b  = f >> 8;
    const int q0 = qb * 64 + w * 16;
    const long base = ((long)(b * 8 + h)) * 2048 * 64;

    const long long first = *reinterpret_cast<const long long*>(masked);
    int kmax;
    if ((first >> 32) != 0) kmax = reinterpret_cast<const int*>(masked)[b];
    else                    kmax = (int)reinterpret_cast<const long long*>(masked)[b];
    kmax = min(max(kmax, 1), 2048);
    const int nkt = (kmax + 63) >> 6;

    // Q fragments (per wave: 16 q-rows)
    const unsigned short* qrow = qp + base + (long)(q0 + nlow) * 64;
    const short8 aq0 = load8(qrow + quad * 8);
    const short8 aq1 = load8(qrow + 32 + quad * 8);

    short8 ones;
#pragma unroll
    for (int j = 0; j < 8; j++) ones[j] = (short)0x3F80;

    f32x4 o_acc[4], lacc;
#pragma unroll
    for (int vb = 0; vb < 4; vb++) o_acc[vb] = (f32x4){0.f, 0.f, 0.f, 0.f};
    lacc = (f32x4){0.f, 0.f, 0.f, 0.f};

    // --- staging descriptors -------------------------------------------------
    const int kr0 = tid >> 3;
    const int kr1 = 32 + kr0;
    const unsigned short* kg0 = kp + base + (long)kr0 * 64 + (((tid & 7) ^ (kr0 & 7)) << 3);
    const unsigned short* kg1 = kp + base + (long)kr1 * 64 + (((tid & 7) ^ (kr1 & 7)) << 3);
    const int kd0 = (w << 9);           // wave-uniform LDS elem offset, round 0
    const int kd1 = 2048 + (w << 9);    // round 1
    const int vk0 = tid >> 3;
    const int vk1 = 32 + vk0;
    const int vd0 = (tid & 7) << 3;
    const unsigned short* vg0 = vp + base + (long)vk0 * 64 + vd0;
    const unsigned short* vg1 = vp + base + (long)vk1 * 64 + vd0;

    // --- prologue: stage tile 0 into buffer 0 --------------------------------
    gload_lds16(kg0, &Ks[0][kd0]);
    gload_lds16(kg1, &Ks[0][kd1]);
    {
        short8 v0 = load8(vg0);
        short8 v1 = load8(vg1);
#pragma unroll
        for (int j = 0; j < 8; j++) {
            Vt[0][vt_idx(vk0, vd0 + j)] = (unsigned short)v0[j];
            Vt[0][vt_idx(vk1, vd0 + j)] = (unsigned short)v1[j];
        }
    }
    __syncthreads();   // drains DMA vmcnt + V ds_writes

    unsigned short* Psw = Ps[w];
    int cur = 0;
    short8 vv0, vv1;

    for (int kt = 0; kt < nkt; kt++) {
        const int k0 = kt * 64;
        const bool more = (kt + 1 < nkt);   // block-uniform
        if (more) {
            const long off = (long)(k0 + 64) * 64;
            gload_lds16(kg0 + off, &Ks[cur ^ 1][kd0]);
            gload_lds16(kg1 + off, &Ks[cur ^ 1][kd1]);
            vv0 = load8(vg0 + off);
            vv1 = load8(vg1 + off);
        }
        const unsigned short* Ksc = Ks[cur];
        const unsigned short* Vtc = Vt[cur];

        // ---- QK^T: 16q x 64k, contraction over dh=64 (2 MFMA per kb) -------
        f32x4 sacc[4];
#pragma unroll
        for (int kb = 0; kb < 4; kb++) sacc[kb] = (f32x4){0.f, 0.f, 0.f, 0.f};
        __builtin_amdgcn_s_setprio(1);
#pragma unroll
        for (int kb = 0; kb < 4; kb++) {
            const int key = kb * 16 + nlow;
            short8 bk0 = load8(Ksc + ks_idx(key, quad));
            short8 bk1 = load8(Ksc + ks_idx(key, 4 + quad));
            sacc[kb] = MFMA16(aq0, bk0, sacc[kb]);
            sacc[kb] = MFMA16(aq1, bk1, sacc[kb]);
        }
        __builtin_amdgcn_s_setprio(0);

        // ---- fixed-offset softmax -> Ps (bf16) ------------------------------
#pragma unroll
        for (int kb = 0; kb < 4; kb++) {
            const bool valid = (k0 + kb * 16 + nlow) < kmax;
#pragma unroll
            for (int r = 0; r < 4; r++) {
                const int q = quad * 4 + r;
                const float e = valid ? fmaf(sacc[kb][r], SCALE_LOG2, -FIXED_M)
                                      : MASKED_E2;
                Psw[ps_idx(q, kb * 16 + nlow)] = f2bf(exp2f(e));
            }
        }
        __threadfence_block();   // same-wave Ps RAW ordering

        // ---- l-sum + PV -----------------------------------------------------
        __builtin_amdgcn_s_setprio(1);
#pragma unroll
        for (int h2 = 0; h2 < 2; h2++) {
            const int g = h2 * 4 + quad;            // key-chunk group
            short8 ap = load8(Psw + ps_idx(nlow, g << 3));
            lacc = MFMA16(ap, ones, lacc);
#pragma unroll
            for (int vb = 0; vb < 4; vb++) {
                short8 bv = load8(Vtc + vt_idx(g << 3, vb * 16 + nlow));
                o_acc[vb] = MFMA16(ap, bv, o_acc[vb]);
            }
        }
        __builtin_amdgcn_s_setprio(0);

        // ---- late half of the async stage: V regs -> LDS --------------------
        if (more) {
            unsigned short* Vtn = Vt[cur ^ 1];
#pragma unroll
            for (int j = 0; j < 8; j++) {
                Vtn[vt_idx(vk0, vd0 + j)] = (unsigned short)vv0[j];
                Vtn[vt_idx(vk1, vd0 + j)] = (unsigned short)vv1[j];
            }
        }
        __syncthreads();   // one barrier per 64-key tile
        cur ^= 1;
    }

    float inv_l[4];
#pragma unroll
    for (int r = 0; r < 4; r++) inv_l[r] = 1.0f / lacc[r];
#pragma unroll
    for (int vb = 0; vb < 4; vb++) {
#pragma unroll
        for (int r = 0; r < 4; r++) {
            const int s   = q0 + quad * 4 + r;
            const int col = h * 64 + vb * 16 + nlow;
            out[(long)(b * 2048 + s) * 512 + col] = f2bf(o_acc[vb][r] * inv_l[r]);
        }
    }
}

// ---------------------------------------------------------------------------
// ws layout (u16 elems):
//   [0)          QKVb   3 x 4194304   (bf16 copies of Q,K,V; Qb aliased by ao)
//   [12582912)   Wb     4 x 262144    (Wq,Wk,Wv,Wo bf16)
//   [13631488)   qp,kp,vp  3 x 4194304
// total 26.2M u16 = 52.4 MB
// ---------------------------------------------------------------------------
extern "C" void kernel_launch(void* const* d_in, const int* in_sizes, int n_in,
                              void* d_out, int out_size, void* d_ws, size_t ws_size,
                              hipStream_t stream)
{
    const float4* Q  = (const float4*)d_in[0];
    const float4* K  = (const float4*)d_in[1];
    const float4* V  = (const float4*)d_in[2];
    const float4* Wq = (const float4*)d_in[3];
    const float*  bq = (const float*)d_in[4];
    const float4* Wk = (const float4*)d_in[5];
    const float*  bk = (const float*)d_in[6];
    const float4* Wv = (const float4*)d_in[7];
    const float*  bv = (const float*)d_in[8];
    const float4* Wo = (const float4*)d_in[9];
    const float*  bo = (const float*)d_in[10];
    const void*   masked = d_in[11];

    unsigned short* ws16 = (unsigned short*)d_ws;
    unsigned short* QKVb = ws16;
    unsigned short* Wb   = ws16 + 12582912;
    unsigned short* qp   = ws16 + 13631488;
    unsigned short* kp   = qp + 4194304;
    unsigned short* vp   = kp + 4194304;
    unsigned short* ao   = ws16;  // alias Qb: Qb consumed before attn writes ao

    convert_bf16<<<2048, 256, 0, stream>>>(Q, K, V, Wq, Wk, Wv, Wo, (u16x4*)ws16);
    gemm_bf<<<dim3(256, 3), 256, 0, stream>>>(QKVb, Wb, bq, bk, bv, qp, 0);
    attn_kernel<<<dim3(1024), 256, 0, stream>>>(qp, kp, vp, masked, ao);
    gemm_bf<<<dim3(256, 1), 256, 0, stream>>>(ao, Wb + 3 * 262144, bo, bo, bo,
                                              d_out, 1);
}